// Round 28
// baseline (260.588 us; speedup 1.0000x reference)
//
#include <hip/hip_runtime.h>
#include <hip/hip_bf16.h>

#define DEV static __device__ __forceinline__

typedef short frag8 __attribute__((ext_vector_type(8)));
typedef float accf4 __attribute__((ext_vector_type(4)));

// Problem constants: B=8, P=576, D=1024, H=16, HD=64, HID=4096, BP=4608, BH=128

DEV unsigned short f2bf(float f){
  union { float f; unsigned int u; } v; v.f = f;
  unsigned int r = v.u + 0x7fffu + ((v.u >> 16) & 1u);
  return (unsigned short)(r >> 16);
}

DEV float bf2f(unsigned short u){
  union { unsigned int i; float f; } v; v.i = (unsigned int)u << 16; return v.f;
}

DEV void gload16(const void* g, void* l){
  __builtin_amdgcn_global_load_lds((const __attribute__((address_space(1))) void*)g,
                                   (__attribute__((address_space(3))) void*)l, 16, 0, 0);
}

DEV float gelu_tanh(float x){
  float u = 0.7978845608028654f * (x + 0.044715f * x * x * x);
  float e = __expf(2.0f * u);
  float th = 1.0f - 2.0f / (e + 1.0f);   // tanh(u), inf-safe
  return 0.5f * x * (1.0f + th);
}

// T1 XCD chunking + GW=16 column-grouped within-chunk mapping.
DEV void block_map(int bid, int nwg, int gx, int& tx, int& ty){
  const int swz = ((nwg & 7) == 0) ? ((bid & 7) * (nwg >> 3) + (bid >> 3)) : bid;
  const int gy = nwg / gx;
  const int cg = swz / (gy * 16);
  const int rr = swz - cg * gy * 16;
  const int gw = min(16, gx - cg * 16);
  tx = cg * 16 + rr % gw;
  ty = rr / gw;
}

// ---------------- fused weight cast+transpose: all 4 weights in one launch ----------------
__global__ __launch_bounds__(256) void wtrans_all(
    const float* __restrict__ Wq, unsigned short* __restrict__ Tq,
    const float* __restrict__ Wp, unsigned short* __restrict__ Tp,
    const float* __restrict__ W1, unsigned short* __restrict__ T1,
    const float* __restrict__ W2, unsigned short* __restrict__ T2){
  __shared__ float t[32][33];
  const int id = blockIdx.x;
  const float* W; unsigned short* Wt; int K, N, idx;
  if (id < 3072)      { W = Wq; Wt = Tq; K = 1024; N = 3072; idx = id; }
  else if (id < 4096) { W = Wp; Wt = Tp; K = 1024; N = 1024; idx = id - 3072; }
  else if (id < 8192) { W = W1; Wt = T1; K = 1024; N = 4096; idx = id - 4096; }
  else                { W = W2; Wt = T2; K = 4096; N = 1024; idx = id - 8192; }
  const int ntx = N >> 5;
  const int n0 = (idx % ntx) * 32, k0 = (idx / ntx) * 32;
  const int tx = threadIdx.x, ty = threadIdx.y;   // (32,8)
  #pragma unroll
  for (int i = 0; i < 4; i++)
    t[ty + i*8][tx] = W[(long)(k0 + ty + i*8) * N + n0 + tx];
  __syncthreads();
  #pragma unroll
  for (int i = 0; i < 4; i++)
    Wt[(long)(n0 + ty + i*8) * K + k0 + tx] = f2bf(t[tx][ty + i*8]);
}

// ---------------- LayerNorm over D=1024 rows -> bf16 out.  BF: input is bf16 ----------------
template<int BF>
__global__ __launch_bounds__(256) void ln_rows(const void* __restrict__ inp,
                                               const float* __restrict__ g,
                                               const float* __restrict__ beta,
                                               unsigned short* __restrict__ out){
  const long row = blockIdx.x;
  const int t = threadIdx.x;
  float4 v;
  if constexpr (BF){
    const ushort4 u = ((const ushort4*)inp)[row * 256 + t];
    v.x = bf2f(u.x); v.y = bf2f(u.y); v.z = bf2f(u.z); v.w = bf2f(u.w);
  } else {
    v = ((const float4*)inp)[row * 256 + t];
  }
  float s  = v.x + v.y + v.z + v.w;
  float s2 = v.x*v.x + v.y*v.y + v.z*v.z + v.w*v.w;
  #pragma unroll
  for (int o = 32; o; o >>= 1){ s += __shfl_xor(s, o); s2 += __shfl_xor(s2, o); }
  __shared__ float rs[4], rq[4];
  const int wv = t >> 6;
  if ((t & 63) == 0){ rs[wv] = s; rq[wv] = s2; }
  __syncthreads();
  s  = rs[0] + rs[1] + rs[2] + rs[3];
  s2 = rq[0] + rq[1] + rq[2] + rq[3];
  const float mean = s * (1.f/1024.f);
  const float inv = rsqrtf(s2 * (1.f/1024.f) - mean*mean + 1e-6f);
  const float4 gv = ((const float4*)g)[t];
  const float4 bv = ((const float4*)beta)[t];
  ushort4 o4;
  o4.x = f2bf((v.x - mean)*inv*gv.x + bv.x);
  o4.y = f2bf((v.y - mean)*inv*gv.y + bv.y);
  o4.z = f2bf((v.z - mean)*inv*gv.z + bv.z);
  o4.w = f2bf((v.w - mean)*inv*gv.w + bv.w);
  *(ushort4*)(out + row * 1024 + t * 4) = o4;
}

// ---------------- flash attention: one block = (bh, 64 q-rows), 4 waves x 16 q-rows ----------------
__global__ __launch_bounds__(256) void attn_k(const unsigned short* __restrict__ Qn,
                                              const unsigned short* __restrict__ Kn,
                                              const unsigned short* __restrict__ Vt,
                                              unsigned short* __restrict__ O){
  __shared__ __align__(16) unsigned short Ks[2][4096];   // [kv 64][d 64] swizzled
  __shared__ __align__(16) unsigned short Vs[2][4096];   // [d 64][kv 64] swizzled
  __shared__ __align__(16) unsigned short Plds[4096];    // per-wave [16 q][64 kv] swizzled
  const int f = blockIdx.x;                  // 1152 blocks; f&7 = XCD
  const int xcd = f & 7, j = f >> 3;         // 144 per XCD
  const int bh = xcd * 16 + j / 9;           // 16 heads per XCD
  const int qb = j - (j / 9) * 9;            // 0..8, 64 q-rows each
  const int b = bh >> 4, h = bh & 15;
  const int tid = threadIdx.x, w = tid >> 6, l = tid & 63;
  const int fr = l & 15, fq = l >> 4;
  const int rsw = fr & 7;
  const int q0 = qb * 64;

  const unsigned short* qbase = Qn + ((long)bh * 576 + q0 + w * 16 + fr) * 64;
  const frag8 qf0 = *(const frag8*)(qbase + fq * 8);
  const frag8 qf1 = *(const frag8*)(qbase + 32 + fq * 8);

  const int r8 = l >> 3;
  const int kq8 = ((l & 7) ^ r8) * 8;
  const unsigned short* kSrc = Kn + ((long)bh * 576 + w * 16 + r8) * 64 + kq8;
  const unsigned short* vSrc = Vt + ((long)bh * 64 + w * 16 + r8) * 576 + kq8;

  auto stage = [&](int d, int t){
    gload16(kSrc + (long)t * 4096,              &Ks[d][w * 1024]);
    gload16(kSrc + (long)t * 4096 + 512,        &Ks[d][w * 1024 + 512]);
    gload16(vSrc + (long)t * 64,                &Vs[d][w * 1024]);
    gload16(vSrc + (long)t * 64 + 8l * 576,     &Vs[d][w * 1024 + 512]);
  };

  accf4 oacc[4];
  #pragma unroll
  for (int nd = 0; nd < 4; nd++) oacc[nd] = (accf4){0.f, 0.f, 0.f, 0.f};
  float m[4] = {-1e30f, -1e30f, -1e30f, -1e30f};
  float lsum[4] = {0.f, 0.f, 0.f, 0.f};

  stage(0, 0);
  __syncthreads();
  int cur = 0;
  for (int t = 0; t < 9; ++t){
    if (t < 8) stage(cur ^ 1, t + 1);

    accf4 st[4];
    #pragma unroll
    for (int kt4 = 0; kt4 < 4; kt4++){
      const int c0 = ((0 * 4 + fq) ^ rsw) * 8;
      const int c1 = ((1 * 4 + fq) ^ rsw) * 8;
      frag8 kf0 = *(const frag8*)&Ks[cur][(kt4 * 16 + fr) * 64 + c0];
      frag8 kf1 = *(const frag8*)&Ks[cur][(kt4 * 16 + fr) * 64 + c1];
      accf4 a = {0.f, 0.f, 0.f, 0.f};
      a = __builtin_amdgcn_mfma_f32_16x16x32_bf16(qf0, kf0, a, 0, 0, 0);
      a = __builtin_amdgcn_mfma_f32_16x16x32_bf16(qf1, kf1, a, 0, 0, 0);
      st[kt4] = a;
    }

    #pragma unroll
    for (int rr = 0; rr < 4; rr++){
      float v = fmaxf(fmaxf(st[0][rr], st[1][rr]), fmaxf(st[2][rr], st[3][rr]));
      #pragma unroll
      for (int o = 8; o; o >>= 1) v = fmaxf(v, __shfl_xor(v, o));
      const float mn = fmaxf(m[rr], v);
      const float sc = __expf(m[rr] - mn);
      float p[4], rs = 0.f;
      #pragma unroll
      for (int kt4 = 0; kt4 < 4; kt4++){ p[kt4] = __expf(st[kt4][rr] - mn); rs += p[kt4]; }
      #pragma unroll
      for (int o = 8; o; o >>= 1) rs += __shfl_xor(rs, o);
      lsum[rr] = lsum[rr] * sc + rs;
      m[rr] = mn;
      #pragma unroll
      for (int nd = 0; nd < 4; nd++) oacc[nd][rr] *= sc;
      const int prow = fq * 4 + rr;
      #pragma unroll
      for (int kt4 = 0; kt4 < 4; kt4++){
        const int chunk = kt4 * 2 + (fr >> 3);
        Plds[w * 1024 + prow * 64 + ((chunk ^ (prow & 7)) << 3) + (fr & 7)] = f2bf(p[kt4]);
      }
    }

    #pragma unroll
    for (int nd = 0; nd < 4; nd++){
      const int c0 = ((0 * 4 + fq) ^ rsw) * 8;
      const int c1 = ((1 * 4 + fq) ^ rsw) * 8;
      frag8 af0 = *(const frag8*)&Plds[w * 1024 + fr * 64 + c0];
      frag8 af1 = *(const frag8*)&Plds[w * 1024 + fr * 64 + c1];
      frag8 vf0 = *(const frag8*)&Vs[cur][(nd * 16 + fr) * 64 + c0];
      frag8 vf1 = *(const frag8*)&Vs[cur][(nd * 16 + fr) * 64 + c1];
      oacc[nd] = __builtin_amdgcn_mfma_f32_16x16x32_bf16(af0, vf0, oacc[nd], 0, 0, 0);
      oacc[nd] = __builtin_amdgcn_mfma_f32_16x16x32_bf16(af1, vf1, oacc[nd], 0, 0, 0);
    }

    __syncthreads();
    cur ^= 1;
  }

  #pragma unroll
  for (int rr = 0; rr < 4; rr++){
    const float rinv = 1.f / lsum[rr];
    const long orow = (long)b * 576 + q0 + w * 16 + fq * 4 + rr;
    #pragma unroll
    for (int nd = 0; nd < 4; nd++)
      O[orow * 1024 + h * 64 + nd * 16 + fr] = f2bf(oacc[nd][rr] * rinv);
  }
}

// ---------------- QKV: 128x128 BK=64, 8 waves (512 thr) -> 4 waves/SIMD at 2 blocks/CU ----------------
// Staging (FIXED): thread tid loads row tid>>3, inverse-swizzled chunk; linear LDS dest
// means wave base = wave*512 ELEMENTS (1024 B); rows 64..127 at element 4096 + wave*512.
// Wave tile 32x64 (wr=wave>>1, wc=wave&1); acc[2][4].
// Epilogue: wave owns one 64-col head-kind; in-wave QK-LN (Q x0.125); V transposed into Vt.
__global__ __launch_bounds__(512) void gemm_qkv8(
    const unsigned short* __restrict__ A, const unsigned short* __restrict__ Bt,
    const float* __restrict__ qg, const float* __restrict__ qb2,
    const float* __restrict__ kg, const float* __restrict__ kb2,
    unsigned short* __restrict__ Qn, unsigned short* __restrict__ Kn,
    unsigned short* __restrict__ Vt,
    int M, int N, int K, int gx)
{
  __shared__ __align__(16) unsigned short As[2][128 * 64];
  __shared__ __align__(16) unsigned short Bs[2][128 * 64];
  const int tid = threadIdx.x;
  const int wave = tid >> 6, l = tid & 63;
  const int fr = l & 15, fq = l >> 4;
  const int wr = wave >> 1, wc = wave & 1;   // 4 x 2 wave grid, wave tile 32x64
  const int rsw = fr & 7;
  int tx, ty;
  block_map(blockIdx.x, gridDim.x, gx, tx, ty);
  const long rowbase = (long)ty * 128;
  const long colbase = (long)tx * 128;

  // staging: thread tid covers row tid>>3 (0..63), chunk inverse-swizzled
  const int r8 = tid >> 3;                   // 0..63
  const int kq = (tid & 7) ^ (r8 & 7);
  const unsigned short* aS = A + (rowbase + r8) * (long)K + kq * 8;
  const unsigned short* bS = Bt + (colbase + r8) * (long)K + kq * 8;

  accf4 acc[2][4];
  const accf4 zero = {0.f, 0.f, 0.f, 0.f};
  #pragma unroll
  for (int m = 0; m < 2; m++)
    #pragma unroll
    for (int n = 0; n < 4; n++) acc[m][n] = zero;

  auto stage = [&](int d, int t){
    const long k0 = (long)t * 64;
    gload16(aS + k0,            &As[d][wave * 512]);
    gload16(aS + 64l*K + k0,    &As[d][4096 + wave * 512]);
    gload16(bS + k0,            &Bs[d][wave * 512]);
    gload16(bS + 64l*K + k0,    &Bs[d][4096 + wave * 512]);
  };
  auto compute = [&](int d){
    #pragma unroll
    for (int kk = 0; kk < 2; kk++){
      const int csw = ((kk * 4 + fq) ^ rsw) * 8;
      frag8 bf[4];
      #pragma unroll
      for (int n = 0; n < 4; n++)
        bf[n] = *(const frag8*)&Bs[d][(wc*64 + n*16 + fr) * 64 + csw];
      #pragma unroll
      for (int m = 0; m < 2; m++){
        frag8 af = *(const frag8*)&As[d][(wr*32 + m*16 + fr) * 64 + csw];
        #pragma unroll
        for (int n = 0; n < 4; n++)
          acc[m][n] = __builtin_amdgcn_mfma_f32_16x16x32_bf16(af, bf[n], acc[m][n], 0, 0, 0);
      }
    }
  };

  const int NT = K >> 6;
  stage(0, 0);
  __syncthreads();
  int cur = 0;
  for (int t = 0; t < NT; ++t){
    if (t + 1 < NT) stage(cur ^ 1, t + 1);
    compute(cur);
    __syncthreads();
    cur ^= 1;
  }

  // epilogue: wave owns 32 rows x 64 cols = one head of one kind
  const int cg = (int)colbase + wc * 64;
  const int kind = cg >> 10;                   // 0=Q, 1=K, 2=V
  const int h = (cg & 1023) >> 6;
  if (kind < 2){
    const float* g  = kind ? kg : qg;
    const float* bb = kind ? kb2 : qb2;
    const float sc = kind ? 1.0f : 0.125f;
    unsigned short* Out = kind ? Kn : Qn;
    #pragma unroll
    for (int m = 0; m < 2; m++){
      #pragma unroll
      for (int r = 0; r < 4; r++){
        float s1 = 0.f, s2 = 0.f;
        #pragma unroll
        for (int n = 0; n < 4; n++){ const float v = acc[m][n][r]; s1 += v; s2 += v*v; }
        #pragma unroll
        for (int o = 8; o; o >>= 1){ s1 += __shfl_xor(s1, o); s2 += __shfl_xor(s2, o); }
        const float mean = s1 * (1.f/64.f);
        const float inv = rsqrtf(s2 * (1.f/64.f) - mean*mean + 1e-6f);
        const long row = rowbase + wr*32 + m*16 + fq*4 + r;
        const int bq = (int)(row / 576), p = (int)(row - (long)bq*576);
        unsigned short* dst = Out + (((long)(bq*16 + h))*576 + p)*64;
        #pragma unroll
        for (int n = 0; n < 4; n++){
          const int d = n*16 + fr;
          dst[d] = f2bf(((acc[m][n][r] - mean)*inv*g[d] + bb[d]) * sc);
        }
      }
    }
  } else {
    #pragma unroll
    for (int m = 0; m < 2; m++){
      const long grow = rowbase + wr*32 + m*16 + fq*4;   // 4 consecutive p (same bq)
      const int bq = (int)(grow / 576), p = (int)(grow - (long)bq*576);
      #pragma unroll
      for (int n = 0; n < 4; n++){
        const int d = n*16 + fr;
        ushort4 o4;
        o4.x = f2bf(acc[m][n][0]); o4.y = f2bf(acc[m][n][1]);
        o4.z = f2bf(acc[m][n][2]); o4.w = f2bf(acc[m][n][3]);
        *(ushort4*)(Vt + ((long)(bq*16 + h)*64 + d)*576 + p) = o4;
      }
    }
  }
}

// ---------------- 128xBN 4-wave BK=64 GEMM, minimum-2-phase + T2 ----------------
// BN=64: LDS 48KB -> 3 blocks/CU.
// EPI 1: Cf = resid + (acc+bias)*ls.  EPI 2: Cb = bf16(gelu(acc+bias)).
template<int BN, int EPI>
__global__ __launch_bounds__(256) void gemm_bk64(
    const unsigned short* __restrict__ A, const unsigned short* __restrict__ Bt,
    float* __restrict__ Cf, unsigned short* __restrict__ Cb,
    const float* __restrict__ bias, const float* __restrict__ ls,
    const float* __restrict__ resid,
    int M, int N, int K, int gx)
{
  constexpr int NF = BN / 32;            // B frags per wave-col
  constexpr int BSLOT = BN / 32;         // B stage slots per wave
  __shared__ __align__(16) unsigned short As[2][128 * 64];
  __shared__ __align__(16) unsigned short Bs[2][BN * 64];
  const int tid = threadIdx.x;
  const int wave = tid >> 6, l = tid & 63;
  const int fr = l & 15, fq = l >> 4;
  const int wr = wave >> 1, wc = wave & 1;
  const int rsw = fr & 7;
  int tx, ty;
  block_map(blockIdx.x, gridDim.x, gx, tx, ty);
  const long rowbase = (long)ty * 128;
  const long colbase = (long)tx * BN;

  const int r8 = l >> 3;
  const int kq = (l & 7) ^ r8;
  const unsigned short* aS = A + (rowbase + wave*32 + r8) * (long)K + kq * 8;
  const unsigned short* bS = Bt + (colbase + wave*(BN/4) + r8) * (long)K + kq * 8;

  accf4 acc[4][NF];
  const accf4 zero = {0.f, 0.f, 0.f, 0.f};
  #pragma unroll
  for (int m = 0; m < 4; m++)
    #pragma unroll
    for (int n = 0; n < NF; n++) acc[m][n] = zero;

  auto stage = [&](int d, int t){
    const long k0 = (long)t * 64;
    #pragma unroll
    for (int s = 0; s < 4; s++)
      gload16(aS + (long)s * 8 * K + k0, &As[d][(wave*4 + s) * 512]);
    #pragma unroll
    for (int s = 0; s < BSLOT; s++)
      gload16(bS + (long)s * 8 * K + k0, &Bs[d][(wave*BSLOT + s) * 512]);
  };
  auto compute = [&](int d){
    #pragma unroll
    for (int kk = 0; kk < 2; kk++){
      const int csw = ((kk * 4 + fq) ^ rsw) * 8;
      frag8 bf[NF];
      #pragma unroll
      for (int n = 0; n < NF; n++)
        bf[n] = *(const frag8*)&Bs[d][(wc*(BN/2) + n*16 + fr) * 64 + csw];
      #pragma unroll
      for (int m = 0; m < 4; m++){
        frag8 af = *(const frag8*)&As[d][(wr*64 + m*16 + fr) * 64 + csw];
        #pragma unroll
        for (int n = 0; n < NF; n++)
          acc[m][n] = __builtin_amdgcn_mfma_f32_16x16x32_bf16(af, bf[n], acc[m][n], 0, 0, 0);
      }
    }
  };

  const int NT = K >> 6;
  stage(0, 0);
  __syncthreads();
  int cur = 0;
  for (int t = 0; t < NT; ++t){
    if (t + 1 < NT) stage(cur ^ 1, t + 1);
    compute(cur);
    __syncthreads();
    cur ^= 1;
  }

  #pragma unroll
  for (int m = 0; m < 4; m++){
    const long rb = rowbase + wr * 64 + m * 16 + fq * 4;
    #pragma unroll
    for (int n = 0; n < NF; n++){
      const long cb = colbase + wc * (BN/2) + n * 16 + fr;
      #pragma unroll
      for (int r = 0; r < 4; r++){
        const long idx = (rb + r) * N + cb;
        const float v = acc[m][n][r];
        if constexpr (EPI == 1){
          Cf[idx] = resid[idx] + (v + bias[cb]) * ls[cb];
        } else {
          Cb[idx] = f2bf(gelu_tanh(v + bias[cb]));
        }
      }
    }
  }
}

extern "C" void kernel_launch(void* const* d_in, const int* in_sizes, int n_in,
                              void* d_out, int out_size, void* d_ws, size_t ws_size,
                              hipStream_t stream){
  (void)in_sizes; (void)n_in; (void)out_size; (void)ws_size;
  const float* x      = (const float*)d_in[0];
  const float* w_qkv  = (const float*)d_in[1];
  const float* q_g    = (const float*)d_in[2];
  const float* q_b    = (const float*)d_in[3];
  const float* k_g    = (const float*)d_in[4];
  const float* k_b    = (const float*)d_in[5];
  const float* o_g    = (const float*)d_in[6];
  const float* o_b    = (const float*)d_in[7];
  const float* w_proj = (const float*)d_in[8];
  const float* b_proj = (const float*)d_in[9];
  const float* ln1_g  = (const float*)d_in[10];
  const float* ln1_b  = (const float*)d_in[11];
  const float* ln2_g  = (const float*)d_in[12];
  const float* ln2_b  = (const float*)d_in[13];
  const float* w1     = (const float*)d_in[14];
  const float* b1     = (const float*)d_in[15];
  const float* w2     = (const float*)d_in[16];
  const float* b2     = (const float*)d_in[17];
  const float* ls1    = (const float*)d_in[18];
  const float* ls2    = (const float*)d_in[19];
  float* out = (float*)d_out;

  char* ws = (char*)d_ws;
  size_t off = 0;
  auto alloc = [&](size_t bytes)->void*{
    void* p = ws + off; off += (bytes + 255) & ~(size_t)255; return p;
  };
  unsigned short* wqkvT  = (unsigned short*)alloc(3072l*1024*2);
  unsigned short* wprojT = (unsigned short*)alloc(1024l*1024*2);
  unsigned short* w1T    = (unsigned short*)alloc(4096l*1024*2);
  unsigned short* w2T    = (unsigned short*)alloc(1024l*4096*2);
  unsigned short* xnA    = (unsigned short*)alloc(4608l*1024*2);   // xn1 / on / xn2
  unsigned short* Qn     = (unsigned short*)alloc(73728l*64*2);
  unsigned short* Kn     = (unsigned short*)alloc(73728l*64*2);
  unsigned short* Vt     = (unsigned short*)alloc(73728l*64*2);
  unsigned short* hbf    = (unsigned short*)alloc(4608l*4096*2);
  unsigned short* attnO  = (unsigned short*)alloc(4608l*1024*2);   // bf16

  // all 4 weights -> bf16 B^T in one launch
  wtrans_all<<<12288, dim3(32,8), 0, stream>>>(w_qkv, wqkvT, w_proj, wprojT,
                                               w1, w1T, w2, w2T);

  // attention branch
  ln_rows<0><<<4608, 256, 0, stream>>>(x, ln1_g, ln1_b, xnA);
  gemm_qkv8<<<24*36, 512, 0, stream>>>(xnA, wqkvT,
                                       q_g, q_b, k_g, k_b, Qn, Kn, Vt,
                                       4608, 3072, 1024, 24);
  attn_k<<<1152, 256, 0, stream>>>(Qn, Kn, Vt, attnO);
  ln_rows<1><<<4608, 256, 0, stream>>>(attnO, o_g, o_b, xnA);
  gemm_bk64<64,1><<<16*36, 256, 0, stream>>>(xnA, wprojT, out, nullptr,
                                             b_proj, ls1, x,
                                             4608, 1024, 1024, 16);
  // MLP branch
  ln_rows<0><<<4608, 256, 0, stream>>>(out, ln2_g, ln2_b, xnA);
  gemm_bk64<64,2><<<64*36, 256, 0, stream>>>(xnA, w1T, nullptr, hbf,
                                             b1, nullptr, nullptr,
                                             4608, 4096, 1024, 64);
  gemm_bk64<64,1><<<16*36, 256, 0, stream>>>(hbf, w2T, out, nullptr,
                                             b2, ls2, out,
                                             4608, 1024, 4096, 16);
}

// Round 29
// 257.864 us; speedup vs baseline: 1.0106x; 1.0106x over previous
//
#include <hip/hip_runtime.h>
#include <hip/hip_bf16.h>

#define DEV static __device__ __forceinline__

typedef short frag8 __attribute__((ext_vector_type(8)));
typedef float accf4 __attribute__((ext_vector_type(4)));

// Problem constants: B=8, P=576, D=1024, H=16, HD=64, HID=4096, BP=4608, BH=128

DEV unsigned short f2bf(float f){
  union { float f; unsigned int u; } v; v.f = f;
  unsigned int r = v.u + 0x7fffu + ((v.u >> 16) & 1u);
  return (unsigned short)(r >> 16);
}

DEV float bf2f(unsigned short u){
  union { unsigned int i; float f; } v; v.i = (unsigned int)u << 16; return v.f;
}

DEV void gload16(const void* g, void* l){
  __builtin_amdgcn_global_load_lds((const __attribute__((address_space(1))) void*)g,
                                   (__attribute__((address_space(3))) void*)l, 16, 0, 0);
}

DEV float gelu_tanh(float x){
  float u = 0.7978845608028654f * (x + 0.044715f * x * x * x);
  float e = __expf(2.0f * u);
  float th = 1.0f - 2.0f / (e + 1.0f);   // tanh(u), inf-safe
  return 0.5f * x * (1.0f + th);
}

// T1 XCD chunking + GW=16 column-grouped within-chunk mapping.
DEV void block_map(int bid, int nwg, int gx, int& tx, int& ty){
  const int swz = ((nwg & 7) == 0) ? ((bid & 7) * (nwg >> 3) + (bid >> 3)) : bid;
  const int gy = nwg / gx;
  const int cg = swz / (gy * 16);
  const int rr = swz - cg * gy * 16;
  const int gw = min(16, gx - cg * 16);
  tx = cg * 16 + rr % gw;
  ty = rr / gw;
}

// ---------------- fused weight cast+transpose: all 4 weights in one launch ----------------
__global__ __launch_bounds__(256) void wtrans_all(
    const float* __restrict__ Wq, unsigned short* __restrict__ Tq,
    const float* __restrict__ Wp, unsigned short* __restrict__ Tp,
    const float* __restrict__ W1, unsigned short* __restrict__ T1,
    const float* __restrict__ W2, unsigned short* __restrict__ T2){
  __shared__ float t[32][33];
  const int id = blockIdx.x;
  const float* W; unsigned short* Wt; int K, N, idx;
  if (id < 3072)      { W = Wq; Wt = Tq; K = 1024; N = 3072; idx = id; }
  else if (id < 4096) { W = Wp; Wt = Tp; K = 1024; N = 1024; idx = id - 3072; }
  else if (id < 8192) { W = W1; Wt = T1; K = 1024; N = 4096; idx = id - 4096; }
  else                { W = W2; Wt = T2; K = 4096; N = 1024; idx = id - 8192; }
  const int ntx = N >> 5;
  const int n0 = (idx % ntx) * 32, k0 = (idx / ntx) * 32;
  const int tx = threadIdx.x, ty = threadIdx.y;   // (32,8)
  #pragma unroll
  for (int i = 0; i < 4; i++)
    t[ty + i*8][tx] = W[(long)(k0 + ty + i*8) * N + n0 + tx];
  __syncthreads();
  #pragma unroll
  for (int i = 0; i < 4; i++)
    Wt[(long)(n0 + ty + i*8) * K + k0 + tx] = f2bf(t[tx][ty + i*8]);
}

// ---------------- LayerNorm over D=1024 rows -> bf16 out.  BF: input is bf16 ----------------
template<int BF>
__global__ __launch_bounds__(256) void ln_rows(const void* __restrict__ inp,
                                               const float* __restrict__ g,
                                               const float* __restrict__ beta,
                                               unsigned short* __restrict__ out){
  const long row = blockIdx.x;
  const int t = threadIdx.x;
  float4 v;
  if constexpr (BF){
    const ushort4 u = ((const ushort4*)inp)[row * 256 + t];
    v.x = bf2f(u.x); v.y = bf2f(u.y); v.z = bf2f(u.z); v.w = bf2f(u.w);
  } else {
    v = ((const float4*)inp)[row * 256 + t];
  }
  float s  = v.x + v.y + v.z + v.w;
  float s2 = v.x*v.x + v.y*v.y + v.z*v.z + v.w*v.w;
  #pragma unroll
  for (int o = 32; o; o >>= 1){ s += __shfl_xor(s, o); s2 += __shfl_xor(s2, o); }
  __shared__ float rs[4], rq[4];
  const int wv = t >> 6;
  if ((t & 63) == 0){ rs[wv] = s; rq[wv] = s2; }
  __syncthreads();
  s  = rs[0] + rs[1] + rs[2] + rs[3];
  s2 = rq[0] + rq[1] + rq[2] + rq[3];
  const float mean = s * (1.f/1024.f);
  const float inv = rsqrtf(s2 * (1.f/1024.f) - mean*mean + 1e-6f);
  const float4 gv = ((const float4*)g)[t];
  const float4 bv = ((const float4*)beta)[t];
  ushort4 o4;
  o4.x = f2bf((v.x - mean)*inv*gv.x + bv.x);
  o4.y = f2bf((v.y - mean)*inv*gv.y + bv.y);
  o4.z = f2bf((v.z - mean)*inv*gv.z + bv.z);
  o4.w = f2bf((v.w - mean)*inv*gv.w + bv.w);
  *(ushort4*)(out + row * 1024 + t * 4) = o4;
}

// ---------------- flash attention: one block = (bh, 64 q-rows), 4 waves x 16 q-rows ----------------
__global__ __launch_bounds__(256) void attn_k(const unsigned short* __restrict__ Qn,
                                              const unsigned short* __restrict__ Kn,
                                              const unsigned short* __restrict__ Vt,
                                              unsigned short* __restrict__ O){
  __shared__ __align__(16) unsigned short Ks[2][4096];   // [kv 64][d 64] swizzled
  __shared__ __align__(16) unsigned short Vs[2][4096];   // [d 64][kv 64] swizzled
  __shared__ __align__(16) unsigned short Plds[4096];    // per-wave [16 q][64 kv] swizzled
  const int f = blockIdx.x;                  // 1152 blocks; f&7 = XCD
  const int xcd = f & 7, j = f >> 3;         // 144 per XCD
  const int bh = xcd * 16 + j / 9;           // 16 heads per XCD
  const int qb = j - (j / 9) * 9;            // 0..8, 64 q-rows each
  const int b = bh >> 4, h = bh & 15;
  const int tid = threadIdx.x, w = tid >> 6, l = tid & 63;
  const int fr = l & 15, fq = l >> 4;
  const int rsw = fr & 7;
  const int q0 = qb * 64;

  const unsigned short* qbase = Qn + ((long)bh * 576 + q0 + w * 16 + fr) * 64;
  const frag8 qf0 = *(const frag8*)(qbase + fq * 8);
  const frag8 qf1 = *(const frag8*)(qbase + 32 + fq * 8);

  const int r8 = l >> 3;
  const int kq8 = ((l & 7) ^ r8) * 8;
  const unsigned short* kSrc = Kn + ((long)bh * 576 + w * 16 + r8) * 64 + kq8;
  const unsigned short* vSrc = Vt + ((long)bh * 64 + w * 16 + r8) * 576 + kq8;

  auto stage = [&](int d, int t){
    gload16(kSrc + (long)t * 4096,              &Ks[d][w * 1024]);
    gload16(kSrc + (long)t * 4096 + 512,        &Ks[d][w * 1024 + 512]);
    gload16(vSrc + (long)t * 64,                &Vs[d][w * 1024]);
    gload16(vSrc + (long)t * 64 + 8l * 576,     &Vs[d][w * 1024 + 512]);
  };

  accf4 oacc[4];
  #pragma unroll
  for (int nd = 0; nd < 4; nd++) oacc[nd] = (accf4){0.f, 0.f, 0.f, 0.f};
  float m[4] = {-1e30f, -1e30f, -1e30f, -1e30f};
  float lsum[4] = {0.f, 0.f, 0.f, 0.f};

  stage(0, 0);
  __syncthreads();
  int cur = 0;
  for (int t = 0; t < 9; ++t){
    if (t < 8) stage(cur ^ 1, t + 1);

    accf4 st[4];
    #pragma unroll
    for (int kt4 = 0; kt4 < 4; kt4++){
      const int c0 = ((0 * 4 + fq) ^ rsw) * 8;
      const int c1 = ((1 * 4 + fq) ^ rsw) * 8;
      frag8 kf0 = *(const frag8*)&Ks[cur][(kt4 * 16 + fr) * 64 + c0];
      frag8 kf1 = *(const frag8*)&Ks[cur][(kt4 * 16 + fr) * 64 + c1];
      accf4 a = {0.f, 0.f, 0.f, 0.f};
      a = __builtin_amdgcn_mfma_f32_16x16x32_bf16(qf0, kf0, a, 0, 0, 0);
      a = __builtin_amdgcn_mfma_f32_16x16x32_bf16(qf1, kf1, a, 0, 0, 0);
      st[kt4] = a;
    }

    #pragma unroll
    for (int rr = 0; rr < 4; rr++){
      float v = fmaxf(fmaxf(st[0][rr], st[1][rr]), fmaxf(st[2][rr], st[3][rr]));
      #pragma unroll
      for (int o = 8; o; o >>= 1) v = fmaxf(v, __shfl_xor(v, o));
      const float mn = fmaxf(m[rr], v);
      const float sc = __expf(m[rr] - mn);
      float p[4], rs = 0.f;
      #pragma unroll
      for (int kt4 = 0; kt4 < 4; kt4++){ p[kt4] = __expf(st[kt4][rr] - mn); rs += p[kt4]; }
      #pragma unroll
      for (int o = 8; o; o >>= 1) rs += __shfl_xor(rs, o);
      lsum[rr] = lsum[rr] * sc + rs;
      m[rr] = mn;
      #pragma unroll
      for (int nd = 0; nd < 4; nd++) oacc[nd][rr] *= sc;
      const int prow = fq * 4 + rr;
      #pragma unroll
      for (int kt4 = 0; kt4 < 4; kt4++){
        const int chunk = kt4 * 2 + (fr >> 3);
        Plds[w * 1024 + prow * 64 + ((chunk ^ (prow & 7)) << 3) + (fr & 7)] = f2bf(p[kt4]);
      }
    }

    #pragma unroll
    for (int nd = 0; nd < 4; nd++){
      const int c0 = ((0 * 4 + fq) ^ rsw) * 8;
      const int c1 = ((1 * 4 + fq) ^ rsw) * 8;
      frag8 af0 = *(const frag8*)&Plds[w * 1024 + fr * 64 + c0];
      frag8 af1 = *(const frag8*)&Plds[w * 1024 + fr * 64 + c1];
      frag8 vf0 = *(const frag8*)&Vs[cur][(nd * 16 + fr) * 64 + c0];
      frag8 vf1 = *(const frag8*)&Vs[cur][(nd * 16 + fr) * 64 + c1];
      oacc[nd] = __builtin_amdgcn_mfma_f32_16x16x32_bf16(af0, vf0, oacc[nd], 0, 0, 0);
      oacc[nd] = __builtin_amdgcn_mfma_f32_16x16x32_bf16(af1, vf1, oacc[nd], 0, 0, 0);
    }

    __syncthreads();
    cur ^= 1;
  }

  #pragma unroll
  for (int rr = 0; rr < 4; rr++){
    const float rinv = 1.f / lsum[rr];
    const long orow = (long)b * 576 + q0 + w * 16 + fq * 4 + rr;
    #pragma unroll
    for (int nd = 0; nd < 4; nd++)
      O[orow * 1024 + h * 64 + nd * 16 + fr] = f2bf(oacc[nd][rr] * rinv);
  }
}

// ---------------- 128xBN 4-wave BK=64 GEMM, minimum-2-phase + T2 ----------------
// BN=64: LDS 48KB -> 3 blocks/CU.  BN=128: 64KB -> 2 blocks/CU.
// EPI 1: Cf = resid + (acc+bias)*ls.  EPI 2: Cb = bf16(gelu(acc+bias)).
// EPI 3 (BN=128, QKV): wave owns one 64-col head-kind; in-wave QK-LN reduce
//   (Q scaled 0.125) -> Qn/Kn bf16; V written TRANSPOSED directly into Vt.
template<int BN, int EPI>
__global__ __launch_bounds__(256) void gemm_bk64(
    const unsigned short* __restrict__ A, const unsigned short* __restrict__ Bt,
    float* __restrict__ Cf, unsigned short* __restrict__ Cb,
    const float* __restrict__ bias, const float* __restrict__ ls,
    const float* __restrict__ resid,
    const float* __restrict__ qg, const float* __restrict__ qb2,
    const float* __restrict__ kg, const float* __restrict__ kb2,
    unsigned short* __restrict__ Qn, unsigned short* __restrict__ Kn,
    unsigned short* __restrict__ Vt,
    int M, int N, int K, int gx)
{
  constexpr int NF = BN / 32;            // B frags per wave-col
  constexpr int BSLOT = BN / 32;         // B stage slots per wave
  __shared__ __align__(16) unsigned short As[2][128 * 64];
  __shared__ __align__(16) unsigned short Bs[2][BN * 64];
  const int tid = threadIdx.x;
  const int wave = tid >> 6, l = tid & 63;
  const int fr = l & 15, fq = l >> 4;
  const int wr = wave >> 1, wc = wave & 1;
  const int rsw = fr & 7;
  int tx, ty;
  block_map(blockIdx.x, gridDim.x, gx, tx, ty);
  const long rowbase = (long)ty * 128;
  const long colbase = (long)tx * BN;

  const int r8 = l >> 3;
  const int kq = (l & 7) ^ r8;
  const unsigned short* aS = A + (rowbase + wave*32 + r8) * (long)K + kq * 8;
  const unsigned short* bS = Bt + (colbase + wave*(BN/4) + r8) * (long)K + kq * 8;

  accf4 acc[4][NF];
  const accf4 zero = {0.f, 0.f, 0.f, 0.f};
  #pragma unroll
  for (int m = 0; m < 4; m++)
    #pragma unroll
    for (int n = 0; n < NF; n++) acc[m][n] = zero;

  auto stage = [&](int d, int t){
    const long k0 = (long)t * 64;
    #pragma unroll
    for (int s = 0; s < 4; s++)
      gload16(aS + (long)s * 8 * K + k0, &As[d][(wave*4 + s) * 512]);
    #pragma unroll
    for (int s = 0; s < BSLOT; s++)
      gload16(bS + (long)s * 8 * K + k0, &Bs[d][(wave*BSLOT + s) * 512]);
  };
  auto compute = [&](int d){
    #pragma unroll
    for (int kk = 0; kk < 2; kk++){
      const int csw = ((kk * 4 + fq) ^ rsw) * 8;
      frag8 bf[NF];
      #pragma unroll
      for (int n = 0; n < NF; n++)
        bf[n] = *(const frag8*)&Bs[d][(wc*(BN/2) + n*16 + fr) * 64 + csw];
      #pragma unroll
      for (int m = 0; m < 4; m++){
        frag8 af = *(const frag8*)&As[d][(wr*64 + m*16 + fr) * 64 + csw];
        #pragma unroll
        for (int n = 0; n < NF; n++)
          acc[m][n] = __builtin_amdgcn_mfma_f32_16x16x32_bf16(af, bf[n], acc[m][n], 0, 0, 0);
      }
    }
  };

  const int NT = K >> 6;
  stage(0, 0);
  __syncthreads();
  int cur = 0;
  for (int t = 0; t < NT; ++t){
    if (t + 1 < NT) stage(cur ^ 1, t + 1);
    compute(cur);
    __syncthreads();
    cur ^= 1;
  }

  if constexpr (EPI == 3){
    // BN=128: wave owns 64 rows x 64 cols = one head of one kind
    const int cg = (int)colbase + wc * 64;
    const int kind = cg >> 10;                   // 0=Q, 1=K, 2=V
    const int h = (cg & 1023) >> 6;
    if (kind < 2){
      const float* g  = kind ? kg : qg;
      const float* bb = kind ? kb2 : qb2;
      const float sc = kind ? 1.0f : 0.125f;
      unsigned short* Out = kind ? Kn : Qn;
      #pragma unroll
      for (int m = 0; m < 4; m++){
        #pragma unroll
        for (int r = 0; r < 4; r++){
          float s1 = 0.f, s2 = 0.f;
          #pragma unroll
          for (int n = 0; n < NF; n++){ const float v = acc[m][n][r]; s1 += v; s2 += v*v; }
          #pragma unroll
          for (int o = 8; o; o >>= 1){ s1 += __shfl_xor(s1, o); s2 += __shfl_xor(s2, o); }
          const float mean = s1 * (1.f/64.f);
          const float inv = rsqrtf(s2 * (1.f/64.f) - mean*mean + 1e-6f);
          const long row = rowbase + wr*64 + m*16 + fq*4 + r;
          const int bq = (int)(row / 576), p = (int)(row - (long)bq*576);
          unsigned short* dst = Out + (((long)(bq*16 + h))*576 + p)*64;
          #pragma unroll
          for (int n = 0; n < NF; n++){
            const int d = n*16 + fr;
            dst[d] = f2bf(((acc[m][n][r] - mean)*inv*g[d] + bb[d]) * sc);
          }
        }
      }
    } else {
      // V: write transposed directly into Vt [BH][64][576], packed 4-p ushort4
      #pragma unroll
      for (int m = 0; m < 4; m++){
        const long grow = rowbase + wr*64 + m*16 + fq*4;   // 4 consecutive p (same bq)
        const int bq = (int)(grow / 576), p = (int)(grow - (long)bq*576);
        #pragma unroll
        for (int n = 0; n < NF; n++){
          const int d = n*16 + fr;
          ushort4 o4;
          o4.x = f2bf(acc[m][n][0]); o4.y = f2bf(acc[m][n][1]);
          o4.z = f2bf(acc[m][n][2]); o4.w = f2bf(acc[m][n][3]);
          *(ushort4*)(Vt + ((long)(bq*16 + h)*64 + d)*576 + p) = o4;
        }
      }
    }
  } else {
    #pragma unroll
    for (int m = 0; m < 4; m++){
      const long rb = rowbase + wr * 64 + m * 16 + fq * 4;
      #pragma unroll
      for (int n = 0; n < NF; n++){
        const long cb = colbase + wc * (BN/2) + n * 16 + fr;
        #pragma unroll
        for (int r = 0; r < 4; r++){
          const long idx = (rb + r) * N + cb;
          const float v = acc[m][n][r];
          if constexpr (EPI == 1){
            Cf[idx] = resid[idx] + (v + bias[cb]) * ls[cb];
          } else {
            Cb[idx] = f2bf(gelu_tanh(v + bias[cb]));
          }
        }
      }
    }
  }
}

extern "C" void kernel_launch(void* const* d_in, const int* in_sizes, int n_in,
                              void* d_out, int out_size, void* d_ws, size_t ws_size,
                              hipStream_t stream){
  (void)in_sizes; (void)n_in; (void)out_size; (void)ws_size;
  const float* x      = (const float*)d_in[0];
  const float* w_qkv  = (const float*)d_in[1];
  const float* q_g    = (const float*)d_in[2];
  const float* q_b    = (const float*)d_in[3];
  const float* k_g    = (const float*)d_in[4];
  const float* k_b    = (const float*)d_in[5];
  const float* o_g    = (const float*)d_in[6];
  const float* o_b    = (const float*)d_in[7];
  const float* w_proj = (const float*)d_in[8];
  const float* b_proj = (const float*)d_in[9];
  const float* ln1_g  = (const float*)d_in[10];
  const float* ln1_b  = (const float*)d_in[11];
  const float* ln2_g  = (const float*)d_in[12];
  const float* ln2_b  = (const float*)d_in[13];
  const float* w1     = (const float*)d_in[14];
  const float* b1     = (const float*)d_in[15];
  const float* w2     = (const float*)d_in[16];
  const float* b2     = (const float*)d_in[17];
  const float* ls1    = (const float*)d_in[18];
  const float* ls2    = (const float*)d_in[19];
  float* out = (float*)d_out;

  char* ws = (char*)d_ws;
  size_t off = 0;
  auto alloc = [&](size_t bytes)->void*{
    void* p = ws + off; off += (bytes + 255) & ~(size_t)255; return p;
  };
  unsigned short* wqkvT  = (unsigned short*)alloc(3072l*1024*2);
  unsigned short* wprojT = (unsigned short*)alloc(1024l*1024*2);
  unsigned short* w1T    = (unsigned short*)alloc(4096l*1024*2);
  unsigned short* w2T    = (unsigned short*)alloc(1024l*4096*2);
  unsigned short* xnA    = (unsigned short*)alloc(4608l*1024*2);   // xn1 / on / xn2
  unsigned short* Qn     = (unsigned short*)alloc(73728l*64*2);
  unsigned short* Kn     = (unsigned short*)alloc(73728l*64*2);
  unsigned short* Vt     = (unsigned short*)alloc(73728l*64*2);
  unsigned short* hbf    = (unsigned short*)alloc(4608l*4096*2);
  unsigned short* attnO  = (unsigned short*)alloc(4608l*1024*2);   // bf16

  // all 4 weights -> bf16 B^T in one launch
  wtrans_all<<<12288, dim3(32,8), 0, stream>>>(w_qkv, wqkvT, w_proj, wprojT,
                                               w1, w1T, w2, w2T);

  // attention branch
  ln_rows<0><<<4608, 256, 0, stream>>>(x, ln1_g, ln1_b, xnA);
  gemm_bk64<128,3><<<24*36, 256, 0, stream>>>(xnA, wqkvT, nullptr, nullptr,
                                              nullptr, nullptr, nullptr,
                                              q_g, q_b, k_g, k_b, Qn, Kn, Vt,
                                              4608, 3072, 1024, 24);
  attn_k<<<1152, 256, 0, stream>>>(Qn, Kn, Vt, attnO);
  ln_rows<1><<<4608, 256, 0, stream>>>(attnO, o_g, o_b, xnA);
  gemm_bk64<64,1><<<16*36, 256, 0, stream>>>(xnA, wprojT, out, nullptr,
                                             b_proj, ls1, x,
                                             nullptr, nullptr, nullptr, nullptr,
                                             nullptr, nullptr, nullptr,
                                             4608, 1024, 1024, 16);
  // MLP branch
  ln_rows<0><<<4608, 256, 0, stream>>>(out, ln2_g, ln2_b, xnA);
  gemm_bk64<64,2><<<64*36, 256, 0, stream>>>(xnA, w1T, nullptr, hbf,
                                             b1, nullptr, nullptr,
                                             nullptr, nullptr, nullptr, nullptr,
                                             nullptr, nullptr, nullptr,
                                             4608, 4096, 1024, 64);
  gemm_bk64<64,1><<<16*36, 256, 0, stream>>>(hbf, w2T, out, nullptr,
                                             b2, ls2, out,
                                             nullptr, nullptr, nullptr, nullptr,
                                             nullptr, nullptr, nullptr,
                                             4608, 1024, 4096, 16);
}

// Round 30
// 256.221 us; speedup vs baseline: 1.0170x; 1.0064x over previous
//
#include <hip/hip_runtime.h>
#include <hip/hip_bf16.h>

#define DEV static __device__ __forceinline__

typedef short frag8 __attribute__((ext_vector_type(8)));
typedef float accf4 __attribute__((ext_vector_type(4)));

// Problem constants: B=8, P=576, D=1024, H=16, HD=64, HID=4096, BP=4608, BH=128

DEV unsigned short f2bf(float f){
  union { float f; unsigned int u; } v; v.f = f;
  unsigned int r = v.u + 0x7fffu + ((v.u >> 16) & 1u);
  return (unsigned short)(r >> 16);
}

DEV float bf2f(unsigned short u){
  union { unsigned int i; float f; } v; v.i = (unsigned int)u << 16; return v.f;
}

DEV void gload16(const void* g, void* l){
  __builtin_amdgcn_global_load_lds((const __attribute__((address_space(1))) void*)g,
                                   (__attribute__((address_space(3))) void*)l, 16, 0, 0);
}

DEV float gelu_tanh(float x){
  float u = 0.7978845608028654f * (x + 0.044715f * x * x * x);
  float e = __expf(2.0f * u);
  float th = 1.0f - 2.0f / (e + 1.0f);   // tanh(u), inf-safe
  return 0.5f * x * (1.0f + th);
}

// T1 XCD chunking + GW=16 column-grouped within-chunk mapping.
DEV void block_map(int bid, int nwg, int gx, int& tx, int& ty){
  const int swz = ((nwg & 7) == 0) ? ((bid & 7) * (nwg >> 3) + (bid >> 3)) : bid;
  const int gy = nwg / gx;
  const int cg = swz / (gy * 16);
  const int rr = swz - cg * gy * 16;
  const int gw = min(16, gx - cg * 16);
  tx = cg * 16 + rr % gw;
  ty = rr / gw;
}

// ---------------- fused: 4 weight transposes + LN1, one launch ----------------
// blocks [0,12288): weight cast+transpose.  [12288,16896): LN1 rows (x f32 -> xnA bf16).
__global__ __launch_bounds__(256) void wtrans_all(
    const float* __restrict__ Wq, unsigned short* __restrict__ Tq,
    const float* __restrict__ Wp, unsigned short* __restrict__ Tp,
    const float* __restrict__ W1, unsigned short* __restrict__ T1,
    const float* __restrict__ W2, unsigned short* __restrict__ T2,
    const float* __restrict__ x, const float* __restrict__ g1,
    const float* __restrict__ b1g, unsigned short* __restrict__ xnA){
  __shared__ float t[32][33];
  __shared__ float rs[4], rq[4];
  const int id = blockIdx.x;
  if (id >= 12288){
    // LN1 row
    const long row = id - 12288;
    const int tt = threadIdx.y * 32 + threadIdx.x;
    const float4 v = ((const float4*)x)[row * 256 + tt];
    float s  = v.x + v.y + v.z + v.w;
    float s2 = v.x*v.x + v.y*v.y + v.z*v.z + v.w*v.w;
    #pragma unroll
    for (int o = 32; o; o >>= 1){ s += __shfl_xor(s, o); s2 += __shfl_xor(s2, o); }
    const int wv = tt >> 6;
    if ((tt & 63) == 0){ rs[wv] = s; rq[wv] = s2; }
    __syncthreads();
    s  = rs[0] + rs[1] + rs[2] + rs[3];
    s2 = rq[0] + rq[1] + rq[2] + rq[3];
    const float mean = s * (1.f/1024.f);
    const float inv = rsqrtf(s2 * (1.f/1024.f) - mean*mean + 1e-6f);
    const float4 gv = ((const float4*)g1)[tt];
    const float4 bv = ((const float4*)b1g)[tt];
    ushort4 o4;
    o4.x = f2bf((v.x - mean)*inv*gv.x + bv.x);
    o4.y = f2bf((v.y - mean)*inv*gv.y + bv.y);
    o4.z = f2bf((v.z - mean)*inv*gv.z + bv.z);
    o4.w = f2bf((v.w - mean)*inv*gv.w + bv.w);
    *(ushort4*)(xnA + row * 1024 + tt * 4) = o4;
    return;
  }
  const float* W; unsigned short* Wt; int K, N, idx;
  if (id < 3072)      { W = Wq; Wt = Tq; K = 1024; N = 3072; idx = id; }
  else if (id < 4096) { W = Wp; Wt = Tp; K = 1024; N = 1024; idx = id - 3072; }
  else if (id < 8192) { W = W1; Wt = T1; K = 1024; N = 4096; idx = id - 4096; }
  else                { W = W2; Wt = T2; K = 4096; N = 1024; idx = id - 8192; }
  const int ntx = N >> 5;
  const int n0 = (idx % ntx) * 32, k0 = (idx / ntx) * 32;
  const int tx = threadIdx.x, ty = threadIdx.y;   // (32,8)
  #pragma unroll
  for (int i = 0; i < 4; i++)
    t[ty + i*8][tx] = W[(long)(k0 + ty + i*8) * N + n0 + tx];
  __syncthreads();
  #pragma unroll
  for (int i = 0; i < 4; i++)
    Wt[(long)(n0 + ty + i*8) * K + k0 + tx] = f2bf(t[tx][ty + i*8]);
}

// ---------------- LayerNorm over D=1024 rows -> bf16 out.  BF: input is bf16 ----------------
template<int BF>
__global__ __launch_bounds__(256) void ln_rows(const void* __restrict__ inp,
                                               const float* __restrict__ g,
                                               const float* __restrict__ beta,
                                               unsigned short* __restrict__ out){
  const long row = blockIdx.x;
  const int t = threadIdx.x;
  float4 v;
  if constexpr (BF){
    const ushort4 u = ((const ushort4*)inp)[row * 256 + t];
    v.x = bf2f(u.x); v.y = bf2f(u.y); v.z = bf2f(u.z); v.w = bf2f(u.w);
  } else {
    v = ((const float4*)inp)[row * 256 + t];
  }
  float s  = v.x + v.y + v.z + v.w;
  float s2 = v.x*v.x + v.y*v.y + v.z*v.z + v.w*v.w;
  #pragma unroll
  for (int o = 32; o; o >>= 1){ s += __shfl_xor(s, o); s2 += __shfl_xor(s2, o); }
  __shared__ float rs[4], rq[4];
  const int wv = t >> 6;
  if ((t & 63) == 0){ rs[wv] = s; rq[wv] = s2; }
  __syncthreads();
  s  = rs[0] + rs[1] + rs[2] + rs[3];
  s2 = rq[0] + rq[1] + rq[2] + rq[3];
  const float mean = s * (1.f/1024.f);
  const float inv = rsqrtf(s2 * (1.f/1024.f) - mean*mean + 1e-6f);
  const float4 gv = ((const float4*)g)[t];
  const float4 bv = ((const float4*)beta)[t];
  ushort4 o4;
  o4.x = f2bf((v.x - mean)*inv*gv.x + bv.x);
  o4.y = f2bf((v.y - mean)*inv*gv.y + bv.y);
  o4.z = f2bf((v.z - mean)*inv*gv.z + bv.z);
  o4.w = f2bf((v.w - mean)*inv*gv.w + bv.w);
  *(ushort4*)(out + row * 1024 + t * 4) = o4;
}

// ---------------- flash attention: one block = (bh, 64 q-rows), 4 waves x 16 q-rows ----------------
__global__ __launch_bounds__(256) void attn_k(const unsigned short* __restrict__ Qn,
                                              const unsigned short* __restrict__ Kn,
                                              const unsigned short* __restrict__ Vt,
                                              unsigned short* __restrict__ O){
  __shared__ __align__(16) unsigned short Ks[2][4096];   // [kv 64][d 64] swizzled
  __shared__ __align__(16) unsigned short Vs[2][4096];   // [d 64][kv 64] swizzled
  __shared__ __align__(16) unsigned short Plds[4096];    // per-wave [16 q][64 kv] swizzled
  const int f = blockIdx.x;                  // 1152 blocks; f&7 = XCD
  const int xcd = f & 7, j = f >> 3;         // 144 per XCD
  const int bh = xcd * 16 + j / 9;           // 16 heads per XCD
  const int qb = j - (j / 9) * 9;            // 0..8, 64 q-rows each
  const int b = bh >> 4, h = bh & 15;
  const int tid = threadIdx.x, w = tid >> 6, l = tid & 63;
  const int fr = l & 15, fq = l >> 4;
  const int rsw = fr & 7;
  const int q0 = qb * 64;

  const unsigned short* qbase = Qn + ((long)bh * 576 + q0 + w * 16 + fr) * 64;
  const frag8 qf0 = *(const frag8*)(qbase + fq * 8);
  const frag8 qf1 = *(const frag8*)(qbase + 32 + fq * 8);

  const int r8 = l >> 3;
  const int kq8 = ((l & 7) ^ r8) * 8;
  const unsigned short* kSrc = Kn + ((long)bh * 576 + w * 16 + r8) * 64 + kq8;
  const unsigned short* vSrc = Vt + ((long)bh * 64 + w * 16 + r8) * 576 + kq8;

  auto stage = [&](int d, int t){
    gload16(kSrc + (long)t * 4096,              &Ks[d][w * 1024]);
    gload16(kSrc + (long)t * 4096 + 512,        &Ks[d][w * 1024 + 512]);
    gload16(vSrc + (long)t * 64,                &Vs[d][w * 1024]);
    gload16(vSrc + (long)t * 64 + 8l * 576,     &Vs[d][w * 1024 + 512]);
  };

  accf4 oacc[4];
  #pragma unroll
  for (int nd = 0; nd < 4; nd++) oacc[nd] = (accf4){0.f, 0.f, 0.f, 0.f};
  float m[4] = {-1e30f, -1e30f, -1e30f, -1e30f};
  float lsum[4] = {0.f, 0.f, 0.f, 0.f};

  stage(0, 0);
  __syncthreads();
  int cur = 0;
  for (int t = 0; t < 9; ++t){
    if (t < 8) stage(cur ^ 1, t + 1);

    accf4 st[4];
    #pragma unroll
    for (int kt4 = 0; kt4 < 4; kt4++){
      const int c0 = ((0 * 4 + fq) ^ rsw) * 8;
      const int c1 = ((1 * 4 + fq) ^ rsw) * 8;
      frag8 kf0 = *(const frag8*)&Ks[cur][(kt4 * 16 + fr) * 64 + c0];
      frag8 kf1 = *(const frag8*)&Ks[cur][(kt4 * 16 + fr) * 64 + c1];
      accf4 a = {0.f, 0.f, 0.f, 0.f};
      a = __builtin_amdgcn_mfma_f32_16x16x32_bf16(qf0, kf0, a, 0, 0, 0);
      a = __builtin_amdgcn_mfma_f32_16x16x32_bf16(qf1, kf1, a, 0, 0, 0);
      st[kt4] = a;
    }

    #pragma unroll
    for (int rr = 0; rr < 4; rr++){
      float v = fmaxf(fmaxf(st[0][rr], st[1][rr]), fmaxf(st[2][rr], st[3][rr]));
      #pragma unroll
      for (int o = 8; o; o >>= 1) v = fmaxf(v, __shfl_xor(v, o));
      const float mn = fmaxf(m[rr], v);
      const float sc = __expf(m[rr] - mn);
      float p[4], rs = 0.f;
      #pragma unroll
      for (int kt4 = 0; kt4 < 4; kt4++){ p[kt4] = __expf(st[kt4][rr] - mn); rs += p[kt4]; }
      #pragma unroll
      for (int o = 8; o; o >>= 1) rs += __shfl_xor(rs, o);
      lsum[rr] = lsum[rr] * sc + rs;
      m[rr] = mn;
      #pragma unroll
      for (int nd = 0; nd < 4; nd++) oacc[nd][rr] *= sc;
      const int prow = fq * 4 + rr;
      #pragma unroll
      for (int kt4 = 0; kt4 < 4; kt4++){
        const int chunk = kt4 * 2 + (fr >> 3);
        Plds[w * 1024 + prow * 64 + ((chunk ^ (prow & 7)) << 3) + (fr & 7)] = f2bf(p[kt4]);
      }
    }

    #pragma unroll
    for (int nd = 0; nd < 4; nd++){
      const int c0 = ((0 * 4 + fq) ^ rsw) * 8;
      const int c1 = ((1 * 4 + fq) ^ rsw) * 8;
      frag8 af0 = *(const frag8*)&Plds[w * 1024 + fr * 64 + c0];
      frag8 af1 = *(const frag8*)&Plds[w * 1024 + fr * 64 + c1];
      frag8 vf0 = *(const frag8*)&Vs[cur][(nd * 16 + fr) * 64 + c0];
      frag8 vf1 = *(const frag8*)&Vs[cur][(nd * 16 + fr) * 64 + c1];
      oacc[nd] = __builtin_amdgcn_mfma_f32_16x16x32_bf16(af0, vf0, oacc[nd], 0, 0, 0);
      oacc[nd] = __builtin_amdgcn_mfma_f32_16x16x32_bf16(af1, vf1, oacc[nd], 0, 0, 0);
    }

    __syncthreads();
    cur ^= 1;
  }

  #pragma unroll
  for (int rr = 0; rr < 4; rr++){
    const float rinv = 1.f / lsum[rr];
    const long orow = (long)b * 576 + q0 + w * 16 + fq * 4 + rr;
    #pragma unroll
    for (int nd = 0; nd < 4; nd++)
      O[orow * 1024 + h * 64 + nd * 16 + fr] = f2bf(oacc[nd][rr] * rinv);
  }
}

// ---------------- 128xBN 4-wave BK=64 GEMM, minimum-2-phase + T2 ----------------
// BN=64: LDS 48KB -> 3 blocks/CU.  BN=128: 64KB -> 2 blocks/CU.
// EPI 1: Cf = resid + (acc+bias)*ls.  EPI 2: Cb = bf16(gelu(acc+bias)).
// EPI 3 (BN=128, QKV): wave owns one 64-col head-kind; in-wave QK-LN reduce
//   (Q scaled 0.125) -> Qn/Kn bf16; V written TRANSPOSED directly into Vt.
template<int BN, int EPI>
__global__ __launch_bounds__(256) void gemm_bk64(
    const unsigned short* __restrict__ A, const unsigned short* __restrict__ Bt,
    float* __restrict__ Cf, unsigned short* __restrict__ Cb,
    const float* __restrict__ bias, const float* __restrict__ ls,
    const float* __restrict__ resid,
    const float* __restrict__ qg, const float* __restrict__ qb2,
    const float* __restrict__ kg, const float* __restrict__ kb2,
    unsigned short* __restrict__ Qn, unsigned short* __restrict__ Kn,
    unsigned short* __restrict__ Vt,
    int M, int N, int K, int gx)
{
  constexpr int NF = BN / 32;            // B frags per wave-col
  constexpr int BSLOT = BN / 32;         // B stage slots per wave
  __shared__ __align__(16) unsigned short As[2][128 * 64];
  __shared__ __align__(16) unsigned short Bs[2][BN * 64];
  const int tid = threadIdx.x;
  const int wave = tid >> 6, l = tid & 63;
  const int fr = l & 15, fq = l >> 4;
  const int wr = wave >> 1, wc = wave & 1;
  const int rsw = fr & 7;
  int tx, ty;
  block_map(blockIdx.x, gridDim.x, gx, tx, ty);
  const long rowbase = (long)ty * 128;
  const long colbase = (long)tx * BN;

  const int r8 = l >> 3;
  const int kq = (l & 7) ^ r8;
  const unsigned short* aS = A + (rowbase + wave*32 + r8) * (long)K + kq * 8;
  const unsigned short* bS = Bt + (colbase + wave*(BN/4) + r8) * (long)K + kq * 8;

  accf4 acc[4][NF];
  const accf4 zero = {0.f, 0.f, 0.f, 0.f};
  #pragma unroll
  for (int m = 0; m < 4; m++)
    #pragma unroll
    for (int n = 0; n < NF; n++) acc[m][n] = zero;

  auto stage = [&](int d, int t){
    const long k0 = (long)t * 64;
    #pragma unroll
    for (int s = 0; s < 4; s++)
      gload16(aS + (long)s * 8 * K + k0, &As[d][(wave*4 + s) * 512]);
    #pragma unroll
    for (int s = 0; s < BSLOT; s++)
      gload16(bS + (long)s * 8 * K + k0, &Bs[d][(wave*BSLOT + s) * 512]);
  };
  auto compute = [&](int d){
    #pragma unroll
    for (int kk = 0; kk < 2; kk++){
      const int csw = ((kk * 4 + fq) ^ rsw) * 8;
      frag8 bf[NF];
      #pragma unroll
      for (int n = 0; n < NF; n++)
        bf[n] = *(const frag8*)&Bs[d][(wc*(BN/2) + n*16 + fr) * 64 + csw];
      #pragma unroll
      for (int m = 0; m < 4; m++){
        frag8 af = *(const frag8*)&As[d][(wr*64 + m*16 + fr) * 64 + csw];
        #pragma unroll
        for (int n = 0; n < NF; n++)
          acc[m][n] = __builtin_amdgcn_mfma_f32_16x16x32_bf16(af, bf[n], acc[m][n], 0, 0, 0);
      }
    }
  };

  const int NT = K >> 6;
  stage(0, 0);
  __syncthreads();
  int cur = 0;
  for (int t = 0; t < NT; ++t){
    if (t + 1 < NT) stage(cur ^ 1, t + 1);
    compute(cur);
    __syncthreads();
    cur ^= 1;
  }

  if constexpr (EPI == 3){
    // BN=128: wave owns 64 rows x 64 cols = one head of one kind
    const int cg = (int)colbase + wc * 64;
    const int kind = cg >> 10;                   // 0=Q, 1=K, 2=V
    const int h = (cg & 1023) >> 6;
    if (kind < 2){
      const float* g  = kind ? kg : qg;
      const float* bb = kind ? kb2 : qb2;
      const float sc = kind ? 1.0f : 0.125f;
      unsigned short* Out = kind ? Kn : Qn;
      #pragma unroll
      for (int m = 0; m < 4; m++){
        #pragma unroll
        for (int r = 0; r < 4; r++){
          float s1 = 0.f, s2 = 0.f;
          #pragma unroll
          for (int n = 0; n < NF; n++){ const float v = acc[m][n][r]; s1 += v; s2 += v*v; }
          #pragma unroll
          for (int o = 8; o; o >>= 1){ s1 += __shfl_xor(s1, o); s2 += __shfl_xor(s2, o); }
          const float mean = s1 * (1.f/64.f);
          const float inv = rsqrtf(s2 * (1.f/64.f) - mean*mean + 1e-6f);
          const long row = rowbase + wr*64 + m*16 + fq*4 + r;
          const int bq = (int)(row / 576), p = (int)(row - (long)bq*576);
          unsigned short* dst = Out + (((long)(bq*16 + h))*576 + p)*64;
          #pragma unroll
          for (int n = 0; n < NF; n++){
            const int d = n*16 + fr;
            dst[d] = f2bf(((acc[m][n][r] - mean)*inv*g[d] + bb[d]) * sc);
          }
        }
      }
    } else {
      // V: write transposed directly into Vt [BH][64][576], packed 4-p ushort4
      #pragma unroll
      for (int m = 0; m < 4; m++){
        const long grow = rowbase + wr*64 + m*16 + fq*4;   // 4 consecutive p (same bq)
        const int bq = (int)(grow / 576), p = (int)(grow - (long)bq*576);
        #pragma unroll
        for (int n = 0; n < NF; n++){
          const int d = n*16 + fr;
          ushort4 o4;
          o4.x = f2bf(acc[m][n][0]); o4.y = f2bf(acc[m][n][1]);
          o4.z = f2bf(acc[m][n][2]); o4.w = f2bf(acc[m][n][3]);
          *(ushort4*)(Vt + ((long)(bq*16 + h)*64 + d)*576 + p) = o4;
        }
      }
    }
  } else {
    #pragma unroll
    for (int m = 0; m < 4; m++){
      const long rb = rowbase + wr * 64 + m * 16 + fq * 4;
      #pragma unroll
      for (int n = 0; n < NF; n++){
        const long cb = colbase + wc * (BN/2) + n * 16 + fr;
        #pragma unroll
        for (int r = 0; r < 4; r++){
          const long idx = (rb + r) * N + cb;
          const float v = acc[m][n][r];
          if constexpr (EPI == 1){
            Cf[idx] = resid[idx] + (v + bias[cb]) * ls[cb];
          } else {
            Cb[idx] = f2bf(gelu_tanh(v + bias[cb]));
          }
        }
      }
    }
  }
}

extern "C" void kernel_launch(void* const* d_in, const int* in_sizes, int n_in,
                              void* d_out, int out_size, void* d_ws, size_t ws_size,
                              hipStream_t stream){
  (void)in_sizes; (void)n_in; (void)out_size; (void)ws_size;
  const float* x      = (const float*)d_in[0];
  const float* w_qkv  = (const float*)d_in[1];
  const float* q_g    = (const float*)d_in[2];
  const float* q_b    = (const float*)d_in[3];
  const float* k_g    = (const float*)d_in[4];
  const float* k_b    = (const float*)d_in[5];
  const float* o_g    = (const float*)d_in[6];
  const float* o_b    = (const float*)d_in[7];
  const float* w_proj = (const float*)d_in[8];
  const float* b_proj = (const float*)d_in[9];
  const float* ln1_g  = (const float*)d_in[10];
  const float* ln1_b  = (const float*)d_in[11];
  const float* ln2_g  = (const float*)d_in[12];
  const float* ln2_b  = (const float*)d_in[13];
  const float* w1     = (const float*)d_in[14];
  const float* b1     = (const float*)d_in[15];
  const float* w2     = (const float*)d_in[16];
  const float* b2     = (const float*)d_in[17];
  const float* ls1    = (const float*)d_in[18];
  const float* ls2    = (const float*)d_in[19];
  float* out = (float*)d_out;

  char* ws = (char*)d_ws;
  size_t off = 0;
  auto alloc = [&](size_t bytes)->void*{
    void* p = ws + off; off += (bytes + 255) & ~(size_t)255; return p;
  };
  unsigned short* wqkvT  = (unsigned short*)alloc(3072l*1024*2);
  unsigned short* wprojT = (unsigned short*)alloc(1024l*1024*2);
  unsigned short* w1T    = (unsigned short*)alloc(4096l*1024*2);
  unsigned short* w2T    = (unsigned short*)alloc(1024l*4096*2);
  unsigned short* xnA    = (unsigned short*)alloc(4608l*1024*2);   // xn1 / on / xn2
  unsigned short* Qn     = (unsigned short*)alloc(73728l*64*2);
  unsigned short* Kn     = (unsigned short*)alloc(73728l*64*2);
  unsigned short* Vt     = (unsigned short*)alloc(73728l*64*2);
  unsigned short* hbf    = (unsigned short*)alloc(4608l*4096*2);
  unsigned short* attnO  = (unsigned short*)alloc(4608l*1024*2);   // bf16

  // fused: weights -> bf16 B^T + LN1 (one launch)
  wtrans_all<<<16896, dim3(32,8), 0, stream>>>(w_qkv, wqkvT, w_proj, wprojT,
                                               w1, w1T, w2, w2T,
                                               x, ln1_g, ln1_b, xnA);

  // attention branch
  gemm_bk64<128,3><<<24*36, 256, 0, stream>>>(xnA, wqkvT, nullptr, nullptr,
                                              nullptr, nullptr, nullptr,
                                              q_g, q_b, k_g, k_b, Qn, Kn, Vt,
                                              4608, 3072, 1024, 24);
  attn_k<<<1152, 256, 0, stream>>>(Qn, Kn, Vt, attnO);
  ln_rows<1><<<4608, 256, 0, stream>>>(attnO, o_g, o_b, xnA);
  gemm_bk64<64,1><<<16*36, 256, 0, stream>>>(xnA, wprojT, out, nullptr,
                                             b_proj, ls1, x,
                                             nullptr, nullptr, nullptr, nullptr,
                                             nullptr, nullptr, nullptr,
                                             4608, 1024, 1024, 16);
  // MLP branch
  ln_rows<0><<<4608, 256, 0, stream>>>(out, ln2_g, ln2_b, xnA);
  gemm_bk64<64,2><<<64*36, 256, 0, stream>>>(xnA, w1T, nullptr, hbf,
                                             b1, nullptr, nullptr,
                                             nullptr, nullptr, nullptr, nullptr,
                                             nullptr, nullptr, nullptr,
                                             4608, 4096, 1024, 64);
  gemm_bk64<64,1><<<16*36, 256, 0, stream>>>(hbf, w2T, out, nullptr,
                                             b2, ls2, out,
                                             nullptr, nullptr, nullptr, nullptr,
                                             nullptr, nullptr, nullptr,
                                             4608, 1024, 4096, 16);
}

// Round 31
// 256.188 us; speedup vs baseline: 1.0172x; 1.0001x over previous
//
#include <hip/hip_runtime.h>
#include <hip/hip_bf16.h>

#define DEV static __device__ __forceinline__

typedef short frag8 __attribute__((ext_vector_type(8)));
typedef float accf4 __attribute__((ext_vector_type(4)));

// Problem constants: B=8, P=576, D=1024, H=16, HD=64, HID=4096, BP=4608, BH=128

DEV unsigned short f2bf(float f){
  union { float f; unsigned int u; } v; v.f = f;
  unsigned int r = v.u + 0x7fffu + ((v.u >> 16) & 1u);
  return (unsigned short)(r >> 16);
}

DEV float bf2f(unsigned short u){
  union { unsigned int i; float f; } v; v.i = (unsigned int)u << 16; return v.f;
}

DEV void gload16(const void* g, void* l){
  __builtin_amdgcn_global_load_lds((const __attribute__((address_space(1))) void*)g,
                                   (__attribute__((address_space(3))) void*)l, 16, 0, 0);
}

DEV float gelu_tanh(float x){
  float u = 0.7978845608028654f * (x + 0.044715f * x * x * x);
  float e = __expf(2.0f * u);
  float th = 1.0f - 2.0f / (e + 1.0f);   // tanh(u), inf-safe
  return 0.5f * x * (1.0f + th);
}

// T1 XCD chunking + GW=16 column-grouped within-chunk mapping.
DEV void block_map(int bid, int nwg, int gx, int& tx, int& ty){
  const int swz = ((nwg & 7) == 0) ? ((bid & 7) * (nwg >> 3) + (bid >> 3)) : bid;
  const int gy = nwg / gx;
  const int cg = swz / (gy * 16);
  const int rr = swz - cg * gy * 16;
  const int gw = min(16, gx - cg * 16);
  tx = cg * 16 + rr % gw;
  ty = rr / gw;
}

// ---------------- fused: 4 weight transposes + LN1, one launch ----------------
// blocks [0,12288): weight cast+transpose.  [12288,16896): LN1 rows (x f32 -> xnA bf16).
__global__ __launch_bounds__(256) void wtrans_all(
    const float* __restrict__ Wq, unsigned short* __restrict__ Tq,
    const float* __restrict__ Wp, unsigned short* __restrict__ Tp,
    const float* __restrict__ W1, unsigned short* __restrict__ T1,
    const float* __restrict__ W2, unsigned short* __restrict__ T2,
    const float* __restrict__ x, const float* __restrict__ g1,
    const float* __restrict__ b1g, unsigned short* __restrict__ xnA){
  __shared__ float t[32][33];
  __shared__ float rs[4], rq[4];
  const int id = blockIdx.x;
  if (id >= 12288){
    // LN1 row
    const long row = id - 12288;
    const int tt = threadIdx.y * 32 + threadIdx.x;
    const float4 v = ((const float4*)x)[row * 256 + tt];
    float s  = v.x + v.y + v.z + v.w;
    float s2 = v.x*v.x + v.y*v.y + v.z*v.z + v.w*v.w;
    #pragma unroll
    for (int o = 32; o; o >>= 1){ s += __shfl_xor(s, o); s2 += __shfl_xor(s2, o); }
    const int wv = tt >> 6;
    if ((tt & 63) == 0){ rs[wv] = s; rq[wv] = s2; }
    __syncthreads();
    s  = rs[0] + rs[1] + rs[2] + rs[3];
    s2 = rq[0] + rq[1] + rq[2] + rq[3];
    const float mean = s * (1.f/1024.f);
    const float inv = rsqrtf(s2 * (1.f/1024.f) - mean*mean + 1e-6f);
    const float4 gv = ((const float4*)g1)[tt];
    const float4 bv = ((const float4*)b1g)[tt];
    ushort4 o4;
    o4.x = f2bf((v.x - mean)*inv*gv.x + bv.x);
    o4.y = f2bf((v.y - mean)*inv*gv.y + bv.y);
    o4.z = f2bf((v.z - mean)*inv*gv.z + bv.z);
    o4.w = f2bf((v.w - mean)*inv*gv.w + bv.w);
    *(ushort4*)(xnA + row * 1024 + tt * 4) = o4;
    return;
  }
  const float* W; unsigned short* Wt; int K, N, idx;
  if (id < 3072)      { W = Wq; Wt = Tq; K = 1024; N = 3072; idx = id; }
  else if (id < 4096) { W = Wp; Wt = Tp; K = 1024; N = 1024; idx = id - 3072; }
  else if (id < 8192) { W = W1; Wt = T1; K = 1024; N = 4096; idx = id - 4096; }
  else                { W = W2; Wt = T2; K = 4096; N = 1024; idx = id - 8192; }
  const int ntx = N >> 5;
  const int n0 = (idx % ntx) * 32, k0 = (idx / ntx) * 32;
  const int tx = threadIdx.x, ty = threadIdx.y;   // (32,8)
  #pragma unroll
  for (int i = 0; i < 4; i++)
    t[ty + i*8][tx] = W[(long)(k0 + ty + i*8) * N + n0 + tx];
  __syncthreads();
  #pragma unroll
  for (int i = 0; i < 4; i++)
    Wt[(long)(n0 + ty + i*8) * K + k0 + tx] = f2bf(t[tx][ty + i*8]);
}

// ---------------- LayerNorm over D=1024 rows -> bf16 out.  BF: input is bf16 ----------------
template<int BF>
__global__ __launch_bounds__(256) void ln_rows(const void* __restrict__ inp,
                                               const float* __restrict__ g,
                                               const float* __restrict__ beta,
                                               unsigned short* __restrict__ out){
  const long row = blockIdx.x;
  const int t = threadIdx.x;
  float4 v;
  if constexpr (BF){
    const ushort4 u = ((const ushort4*)inp)[row * 256 + t];
    v.x = bf2f(u.x); v.y = bf2f(u.y); v.z = bf2f(u.z); v.w = bf2f(u.w);
  } else {
    v = ((const float4*)inp)[row * 256 + t];
  }
  float s  = v.x + v.y + v.z + v.w;
  float s2 = v.x*v.x + v.y*v.y + v.z*v.z + v.w*v.w;
  #pragma unroll
  for (int o = 32; o; o >>= 1){ s += __shfl_xor(s, o); s2 += __shfl_xor(s2, o); }
  __shared__ float rs[4], rq[4];
  const int wv = t >> 6;
  if ((t & 63) == 0){ rs[wv] = s; rq[wv] = s2; }
  __syncthreads();
  s  = rs[0] + rs[1] + rs[2] + rs[3];
  s2 = rq[0] + rq[1] + rq[2] + rq[3];
  const float mean = s * (1.f/1024.f);
  const float inv = rsqrtf(s2 * (1.f/1024.f) - mean*mean + 1e-6f);
  const float4 gv = ((const float4*)g)[t];
  const float4 bv = ((const float4*)beta)[t];
  ushort4 o4;
  o4.x = f2bf((v.x - mean)*inv*gv.x + bv.x);
  o4.y = f2bf((v.y - mean)*inv*gv.y + bv.y);
  o4.z = f2bf((v.z - mean)*inv*gv.z + bv.z);
  o4.w = f2bf((v.w - mean)*inv*gv.w + bv.w);
  *(ushort4*)(out + row * 1024 + t * 4) = o4;
}

// ---------------- flash attention: one block = (bh, 64 q-rows), 4 waves x 16 q-rows ----------------
__global__ __launch_bounds__(256) void attn_k(const unsigned short* __restrict__ Qn,
                                              const unsigned short* __restrict__ Kn,
                                              const unsigned short* __restrict__ Vt,
                                              unsigned short* __restrict__ O){
  __shared__ __align__(16) unsigned short Ks[2][4096];   // [kv 64][d 64] swizzled
  __shared__ __align__(16) unsigned short Vs[2][4096];   // [d 64][kv 64] swizzled
  __shared__ __align__(16) unsigned short Plds[4096];    // per-wave [16 q][64 kv] swizzled
  const int f = blockIdx.x;                  // 1152 blocks; f&7 = XCD
  const int xcd = f & 7, j = f >> 3;         // 144 per XCD
  const int bh = xcd * 16 + j / 9;           // 16 heads per XCD
  const int qb = j - (j / 9) * 9;            // 0..8, 64 q-rows each
  const int b = bh >> 4, h = bh & 15;
  const int tid = threadIdx.x, w = tid >> 6, l = tid & 63;
  const int fr = l & 15, fq = l >> 4;
  const int rsw = fr & 7;
  const int q0 = qb * 64;

  const unsigned short* qbase = Qn + ((long)bh * 576 + q0 + w * 16 + fr) * 64;
  const frag8 qf0 = *(const frag8*)(qbase + fq * 8);
  const frag8 qf1 = *(const frag8*)(qbase + 32 + fq * 8);

  const int r8 = l >> 3;
  const int kq8 = ((l & 7) ^ r8) * 8;
  const unsigned short* kSrc = Kn + ((long)bh * 576 + w * 16 + r8) * 64 + kq8;
  const unsigned short* vSrc = Vt + ((long)bh * 64 + w * 16 + r8) * 576 + kq8;

  auto stage = [&](int d, int t){
    gload16(kSrc + (long)t * 4096,              &Ks[d][w * 1024]);
    gload16(kSrc + (long)t * 4096 + 512,        &Ks[d][w * 1024 + 512]);
    gload16(vSrc + (long)t * 64,                &Vs[d][w * 1024]);
    gload16(vSrc + (long)t * 64 + 8l * 576,     &Vs[d][w * 1024 + 512]);
  };

  accf4 oacc[4];
  #pragma unroll
  for (int nd = 0; nd < 4; nd++) oacc[nd] = (accf4){0.f, 0.f, 0.f, 0.f};
  float m[4] = {-1e30f, -1e30f, -1e30f, -1e30f};
  float lsum[4] = {0.f, 0.f, 0.f, 0.f};

  stage(0, 0);
  __syncthreads();
  int cur = 0;
  for (int t = 0; t < 9; ++t){
    if (t < 8) stage(cur ^ 1, t + 1);

    accf4 st[4];
    #pragma unroll
    for (int kt4 = 0; kt4 < 4; kt4++){
      const int c0 = ((0 * 4 + fq) ^ rsw) * 8;
      const int c1 = ((1 * 4 + fq) ^ rsw) * 8;
      frag8 kf0 = *(const frag8*)&Ks[cur][(kt4 * 16 + fr) * 64 + c0];
      frag8 kf1 = *(const frag8*)&Ks[cur][(kt4 * 16 + fr) * 64 + c1];
      accf4 a = {0.f, 0.f, 0.f, 0.f};
      a = __builtin_amdgcn_mfma_f32_16x16x32_bf16(qf0, kf0, a, 0, 0, 0);
      a = __builtin_amdgcn_mfma_f32_16x16x32_bf16(qf1, kf1, a, 0, 0, 0);
      st[kt4] = a;
    }

    #pragma unroll
    for (int rr = 0; rr < 4; rr++){
      float v = fmaxf(fmaxf(st[0][rr], st[1][rr]), fmaxf(st[2][rr], st[3][rr]));
      #pragma unroll
      for (int o = 8; o; o >>= 1) v = fmaxf(v, __shfl_xor(v, o));
      const float mn = fmaxf(m[rr], v);
      const float sc = __expf(m[rr] - mn);
      float p[4], rs = 0.f;
      #pragma unroll
      for (int kt4 = 0; kt4 < 4; kt4++){ p[kt4] = __expf(st[kt4][rr] - mn); rs += p[kt4]; }
      #pragma unroll
      for (int o = 8; o; o >>= 1) rs += __shfl_xor(rs, o);
      lsum[rr] = lsum[rr] * sc + rs;
      m[rr] = mn;
      #pragma unroll
      for (int nd = 0; nd < 4; nd++) oacc[nd][rr] *= sc;
      const int prow = fq * 4 + rr;
      #pragma unroll
      for (int kt4 = 0; kt4 < 4; kt4++){
        const int chunk = kt4 * 2 + (fr >> 3);
        Plds[w * 1024 + prow * 64 + ((chunk ^ (prow & 7)) << 3) + (fr & 7)] = f2bf(p[kt4]);
      }
    }

    #pragma unroll
    for (int nd = 0; nd < 4; nd++){
      const int c0 = ((0 * 4 + fq) ^ rsw) * 8;
      const int c1 = ((1 * 4 + fq) ^ rsw) * 8;
      frag8 af0 = *(const frag8*)&Plds[w * 1024 + fr * 64 + c0];
      frag8 af1 = *(const frag8*)&Plds[w * 1024 + fr * 64 + c1];
      frag8 vf0 = *(const frag8*)&Vs[cur][(nd * 16 + fr) * 64 + c0];
      frag8 vf1 = *(const frag8*)&Vs[cur][(nd * 16 + fr) * 64 + c1];
      oacc[nd] = __builtin_amdgcn_mfma_f32_16x16x32_bf16(af0, vf0, oacc[nd], 0, 0, 0);
      oacc[nd] = __builtin_amdgcn_mfma_f32_16x16x32_bf16(af1, vf1, oacc[nd], 0, 0, 0);
    }

    __syncthreads();
    cur ^= 1;
  }

  #pragma unroll
  for (int rr = 0; rr < 4; rr++){
    const float rinv = 1.f / lsum[rr];
    const long orow = (long)b * 576 + q0 + w * 16 + fq * 4 + rr;
    #pragma unroll
    for (int nd = 0; nd < 4; nd++)
      O[orow * 1024 + h * 64 + nd * 16 + fr] = f2bf(oacc[nd][rr] * rinv);
  }
}

// ---------------- 128xBN 4-wave BK=64 GEMM, minimum-2-phase + T2 ----------------
// BN=64: LDS 48KB -> 3 blocks/CU.  BN=128: 64KB -> 2 blocks/CU.
// EPI 1: Cf = resid + (acc+bias)*ls.  EPI 2: Cb = bf16(gelu(acc+bias)).
// EPI 3 (BN=128, QKV): wave owns one 64-col head-kind; in-wave QK-LN reduce
//   (Q scaled 0.125) -> Qn/Kn bf16; V written TRANSPOSED directly into Vt.
template<int BN, int EPI>
__global__ __launch_bounds__(256) void gemm_bk64(
    const unsigned short* __restrict__ A, const unsigned short* __restrict__ Bt,
    float* __restrict__ Cf, unsigned short* __restrict__ Cb,
    const float* __restrict__ bias, const float* __restrict__ ls,
    const float* __restrict__ resid,
    const float* __restrict__ qg, const float* __restrict__ qb2,
    const float* __restrict__ kg, const float* __restrict__ kb2,
    unsigned short* __restrict__ Qn, unsigned short* __restrict__ Kn,
    unsigned short* __restrict__ Vt,
    int M, int N, int K, int gx)
{
  constexpr int NF = BN / 32;            // B frags per wave-col
  constexpr int BSLOT = BN / 32;         // B stage slots per wave
  __shared__ __align__(16) unsigned short As[2][128 * 64];
  __shared__ __align__(16) unsigned short Bs[2][BN * 64];
  const int tid = threadIdx.x;
  const int wave = tid >> 6, l = tid & 63;
  const int fr = l & 15, fq = l >> 4;
  const int wr = wave >> 1, wc = wave & 1;
  const int rsw = fr & 7;
  int tx, ty;
  block_map(blockIdx.x, gridDim.x, gx, tx, ty);
  const long rowbase = (long)ty * 128;
  const long colbase = (long)tx * BN;

  const int r8 = l >> 3;
  const int kq = (l & 7) ^ r8;
  const unsigned short* aS = A + (rowbase + wave*32 + r8) * (long)K + kq * 8;
  const unsigned short* bS = Bt + (colbase + wave*(BN/4) + r8) * (long)K + kq * 8;

  accf4 acc[4][NF];
  const accf4 zero = {0.f, 0.f, 0.f, 0.f};
  #pragma unroll
  for (int m = 0; m < 4; m++)
    #pragma unroll
    for (int n = 0; n < NF; n++) acc[m][n] = zero;

  auto stage = [&](int d, int t){
    const long k0 = (long)t * 64;
    #pragma unroll
    for (int s = 0; s < 4; s++)
      gload16(aS + (long)s * 8 * K + k0, &As[d][(wave*4 + s) * 512]);
    #pragma unroll
    for (int s = 0; s < BSLOT; s++)
      gload16(bS + (long)s * 8 * K + k0, &Bs[d][(wave*BSLOT + s) * 512]);
  };
  auto compute = [&](int d){
    #pragma unroll
    for (int kk = 0; kk < 2; kk++){
      const int csw = ((kk * 4 + fq) ^ rsw) * 8;
      frag8 bf[NF];
      #pragma unroll
      for (int n = 0; n < NF; n++)
        bf[n] = *(const frag8*)&Bs[d][(wc*(BN/2) + n*16 + fr) * 64 + csw];
      #pragma unroll
      for (int m = 0; m < 4; m++){
        frag8 af = *(const frag8*)&As[d][(wr*64 + m*16 + fr) * 64 + csw];
        #pragma unroll
        for (int n = 0; n < NF; n++)
          acc[m][n] = __builtin_amdgcn_mfma_f32_16x16x32_bf16(af, bf[n], acc[m][n], 0, 0, 0);
      }
    }
  };

  const int NT = K >> 6;
  stage(0, 0);
  __syncthreads();
  int cur = 0;
  for (int t = 0; t < NT; ++t){
    if (t + 1 < NT) stage(cur ^ 1, t + 1);
    compute(cur);
    __syncthreads();
    cur ^= 1;
  }

  if constexpr (EPI == 3){
    // BN=128: wave owns 64 rows x 64 cols = one head of one kind
    const int cg = (int)colbase + wc * 64;
    const int kind = cg >> 10;                   // 0=Q, 1=K, 2=V
    const int h = (cg & 1023) >> 6;
    if (kind < 2){
      const float* g  = kind ? kg : qg;
      const float* bb = kind ? kb2 : qb2;
      const float sc = kind ? 1.0f : 0.125f;
      unsigned short* Out = kind ? Kn : Qn;
      #pragma unroll
      for (int m = 0; m < 4; m++){
        #pragma unroll
        for (int r = 0; r < 4; r++){
          float s1 = 0.f, s2 = 0.f;
          #pragma unroll
          for (int n = 0; n < NF; n++){ const float v = acc[m][n][r]; s1 += v; s2 += v*v; }
          #pragma unroll
          for (int o = 8; o; o >>= 1){ s1 += __shfl_xor(s1, o); s2 += __shfl_xor(s2, o); }
          const float mean = s1 * (1.f/64.f);
          const float inv = rsqrtf(s2 * (1.f/64.f) - mean*mean + 1e-6f);
          const long row = rowbase + wr*64 + m*16 + fq*4 + r;
          const int bq = (int)(row / 576), p = (int)(row - (long)bq*576);
          unsigned short* dst = Out + (((long)(bq*16 + h))*576 + p)*64;
          #pragma unroll
          for (int n = 0; n < NF; n++){
            const int d = n*16 + fr;
            dst[d] = f2bf(((acc[m][n][r] - mean)*inv*g[d] + bb[d]) * sc);
          }
        }
      }
    } else {
      // V: write transposed directly into Vt [BH][64][576], packed 4-p ushort4
      #pragma unroll
      for (int m = 0; m < 4; m++){
        const long grow = rowbase + wr*64 + m*16 + fq*4;   // 4 consecutive p (same bq)
        const int bq = (int)(grow / 576), p = (int)(grow - (long)bq*576);
        #pragma unroll
        for (int n = 0; n < NF; n++){
          const int d = n*16 + fr;
          ushort4 o4;
          o4.x = f2bf(acc[m][n][0]); o4.y = f2bf(acc[m][n][1]);
          o4.z = f2bf(acc[m][n][2]); o4.w = f2bf(acc[m][n][3]);
          *(ushort4*)(Vt + ((long)(bq*16 + h)*64 + d)*576 + p) = o4;
        }
      }
    }
  } else {
    #pragma unroll
    for (int m = 0; m < 4; m++){
      const long rb = rowbase + wr * 64 + m * 16 + fq * 4;
      #pragma unroll
      for (int n = 0; n < NF; n++){
        const long cb = colbase + wc * (BN/2) + n * 16 + fr;
        #pragma unroll
        for (int r = 0; r < 4; r++){
          const long idx = (rb + r) * N + cb;
          const float v = acc[m][n][r];
          if constexpr (EPI == 1){
            Cf[idx] = resid[idx] + (v + bias[cb]) * ls[cb];
          } else {
            Cb[idx] = f2bf(gelu_tanh(v + bias[cb]));
          }
        }
      }
    }
  }
}

extern "C" void kernel_launch(void* const* d_in, const int* in_sizes, int n_in,
                              void* d_out, int out_size, void* d_ws, size_t ws_size,
                              hipStream_t stream){
  (void)in_sizes; (void)n_in; (void)out_size; (void)ws_size;
  const float* x      = (const float*)d_in[0];
  const float* w_qkv  = (const float*)d_in[1];
  const float* q_g    = (const float*)d_in[2];
  const float* q_b    = (const float*)d_in[3];
  const float* k_g    = (const float*)d_in[4];
  const float* k_b    = (const float*)d_in[5];
  const float* o_g    = (const float*)d_in[6];
  const float* o_b    = (const float*)d_in[7];
  const float* w_proj = (const float*)d_in[8];
  const float* b_proj = (const float*)d_in[9];
  const float* ln1_g  = (const float*)d_in[10];
  const float* ln1_b  = (const float*)d_in[11];
  const float* ln2_g  = (const float*)d_in[12];
  const float* ln2_b  = (const float*)d_in[13];
  const float* w1     = (const float*)d_in[14];
  const float* b1     = (const float*)d_in[15];
  const float* w2     = (const float*)d_in[16];
  const float* b2     = (const float*)d_in[17];
  const float* ls1    = (const float*)d_in[18];
  const float* ls2    = (const float*)d_in[19];
  float* out = (float*)d_out;

  char* ws = (char*)d_ws;
  size_t off = 0;
  auto alloc = [&](size_t bytes)->void*{
    void* p = ws + off; off += (bytes + 255) & ~(size_t)255; return p;
  };
  unsigned short* wqkvT  = (unsigned short*)alloc(3072l*1024*2);
  unsigned short* wprojT = (unsigned short*)alloc(1024l*1024*2);
  unsigned short* w1T    = (unsigned short*)alloc(4096l*1024*2);
  unsigned short* w2T    = (unsigned short*)alloc(1024l*4096*2);
  unsigned short* xnA    = (unsigned short*)alloc(4608l*1024*2);   // xn1 / on / xn2
  unsigned short* Qn     = (unsigned short*)alloc(73728l*64*2);
  unsigned short* Kn     = (unsigned short*)alloc(73728l*64*2);
  unsigned short* Vt     = (unsigned short*)alloc(73728l*64*2);
  unsigned short* hbf    = (unsigned short*)alloc(4608l*4096*2);
  unsigned short* attnO  = (unsigned short*)alloc(4608l*1024*2);   // bf16

  // fused: weights -> bf16 B^T + LN1 (one launch)
  wtrans_all<<<16896, dim3(32,8), 0, stream>>>(w_qkv, wqkvT, w_proj, wprojT,
                                               w1, w1T, w2, w2T,
                                               x, ln1_g, ln1_b, xnA);

  // attention branch
  gemm_bk64<128,3><<<24*36, 256, 0, stream>>>(xnA, wqkvT, nullptr, nullptr,
                                              nullptr, nullptr, nullptr,
                                              q_g, q_b, k_g, k_b, Qn, Kn, Vt,
                                              4608, 3072, 1024, 24);
  attn_k<<<1152, 256, 0, stream>>>(Qn, Kn, Vt, attnO);
  ln_rows<1><<<4608, 256, 0, stream>>>(attnO, o_g, o_b, xnA);
  gemm_bk64<64,1><<<16*36, 256, 0, stream>>>(xnA, wprojT, out, nullptr,
                                             b_proj, ls1, x,
                                             nullptr, nullptr, nullptr, nullptr,
                                             nullptr, nullptr, nullptr,
                                             4608, 1024, 1024, 16);
  // MLP branch
  ln_rows<0><<<4608, 256, 0, stream>>>(out, ln2_g, ln2_b, xnA);
  gemm_bk64<64,2><<<64*36, 256, 0, stream>>>(xnA, w1T, nullptr, hbf,
                                             b1, nullptr, nullptr,
                                             nullptr, nullptr, nullptr, nullptr,
                                             nullptr, nullptr, nullptr,
                                             4608, 4096, 1024, 64);
  gemm_bk64<64,1><<<16*36, 256, 0, stream>>>(hbf, w2T, out, nullptr,
                                             b2, ls2, out,
                                             nullptr, nullptr, nullptr, nullptr,
                                             nullptr, nullptr, nullptr,
                                             4608, 1024, 4096, 16);
}